// Round 8
// baseline (820.604 us; speedup 1.0000x reference)
//
#include <hip/hip_runtime.h>

#define NODE_DIM 8

typedef __attribute__((ext_vector_type(8))) short short8;
typedef __attribute__((ext_vector_type(4))) float f32x4;

// 8-term dot; param must not be named w/x/y/z (macro hits member access).
#define DOT8(xv, WT) ((xv)[0]*(WT)[0] + (xv)[1]*(WT)[1] + (xv)[2]*(WT)[2] + (xv)[3]*(WT)[3] + \
                      (xv)[4]*(WT)[4] + (xv)[5]*(WT)[5] + (xv)[6]*(WT)[6] + (xv)[7]*(WT)[7])

// Single-instruction RNE fp32 pair -> packed bf16x2 (a -> low16, b -> high16).
static __device__ __forceinline__ unsigned cvt_pk_bf16(float a, float b) {
    unsigned r;
    asm("v_cvt_pk_bf16_f32 %0, %1, %2" : "=v"(r) : "v"(a), "v"(b));
    return r;
}

// ===========================================================================
// R12: fused kernel with FAST grid barrier. R11 decomposition: fused total
// pipe busy-time == sum of phases (VALU 29us==R8's 32, MFMA 7.3==7.2), but
// wall time 442us vs ~190us of phase work -> cg::this_grid().sync() costs
// ~84us each (slow s_sleep backoff in ROCm's two-level barrier). Fix:
// generation-based hand-rolled barrier (~3-5us): device-scope atomic cnt,
// last arriver resets cnt + release-bumps gen, spinners acquire-poll gen.
// Self-resetting -> graph-replay safe. Zeroing moved back to host memset
// (one dispatch, also zeroes the barrier). 2 dispatches total, 2 barriers.
// Residency guaranteed by hipLaunchCooperativeKernel (launched fine in R11);
// fallback = proven R8 3-kernel path.
// ===========================================================================

static __device__ __forceinline__ void grid_sync(int* bar, int nb) {
    __threadfence();                 // release: my writes visible device-wide
    __syncthreads();                 // whole block arrived + fenced
    if (threadIdx.x == 0) {
        int* cnt = bar;
        int* gen = bar + 1;
        const int g    = __hip_atomic_load(gen, __ATOMIC_ACQUIRE, __HIP_MEMORY_SCOPE_AGENT);
        const int prev = __hip_atomic_fetch_add(cnt, 1, __ATOMIC_ACQ_REL, __HIP_MEMORY_SCOPE_AGENT);
        if (prev == nb - 1) {
            // last arriver: reset cnt for next use, then release waiters
            __hip_atomic_store(cnt, 0, __ATOMIC_RELAXED, __HIP_MEMORY_SCOPE_AGENT);
            __hip_atomic_fetch_add(gen, 1, __ATOMIC_RELEASE, __HIP_MEMORY_SCOPE_AGENT);
        } else {
            while (__hip_atomic_load(gen, __ATOMIC_ACQUIRE, __HIP_MEMORY_SCOPE_AGENT) == g)
                __builtin_amdgcn_s_sleep(2);
        }
    }
    __syncthreads();
    __threadfence();                 // acquire: drop stale cached lines
}

// ---- phase: stage B fragments (bf16, frag-order) into LDS -----------------
static __device__ __forceinline__ void stage_b_frags(short* lds_b,
                                                     const float* __restrict__ W2,
                                                     const float* __restrict__ b2)
{
    const int t = threadIdx.x;
    for (int f = t; f < 18 * 64 * 8; f += 256) {
        const int j   = f & 7;
        const int ln  = (f >> 3) & 63;
        const int fid = f >> 9;            // 0..17
        const int kk  = fid >> 1, ot = fid & 1;
        const int qq  = ln >> 4, ol = ln & 15;
        float v;
        if (kk < 8) v = W2[(kk * 4 + qq) * 256 + j * 32 + ot * 16 + ol];
        else        v = (qq == 0) ? b2[j * 32 + ot * 16 + ol] : 0.f;
        unsigned uv = __float_as_uint(v);
        uv = (uv + 0x7fffu + ((uv >> 16) & 1u)) >> 16;
        lds_b[f] = (short)uv;
    }
}

// ---- phase: edge MFMA + scatter-mean atomics (R8 logic) -------------------
static __device__ __forceinline__ void edge_compute(const short* lds_b,
                                                    const float* __restrict__ x,
                                                    const float* __restrict__ ea,
                                                    const int* __restrict__ eidx,
                                                    const float* __restrict__ W1,
                                                    const float* __restrict__ b1,
                                                    float* __restrict__ s,
                                                    int* __restrict__ cnt,
                                                    int E)
{
    const int t    = threadIdx.x;
    const int lane = t & 63;
    const int e_l  = lane & 15;    // edge slot within group (A: m, C: n!)
    const int q    = lane >> 4;    // quad

    // W1 columns for this lane's h set: k = 4t+q.
    float w10[8], w11[8], w12[8], b1r[8];
#pragma unroll
    for (int t2 = 0; t2 < 8; ++t2) {
        const int k = 4 * t2 + q;
        w10[t2] = W1[k]; w11[t2] = W1[32 + k]; w12[t2] = W1[64 + k]; b1r[t2] = b1[k];
    }

    const int wave = blockIdx.x * 4 + (t >> 6);
    const int nwav = gridDim.x * 4;
    const int ngrp = (E + 15) / 16;

    for (int g0 = 2 * wave; g0 < ngrp; g0 += 2 * nwav) {
        const bool v1    = (g0 + 1) < ngrp;
        const int  base0 = g0 * 16;
        const int  base1 = (v1 ? g0 + 1 : g0) * 16;

        int ej0 = base0 + e_l; if (ej0 >= E) ej0 = E - 1;
        int ej1 = base1 + e_l; if (ej1 >= E) ej1 = E - 1;

        // ---- all global loads for both groups issued up front ----
        const int src0 = eidx[ej0];
        const int dst0 = eidx[E + ej0];
        const int src1 = eidx[ej1];
        const int dst1 = eidx[E + ej1];
        const float ea00 = ea[3 * ej0], ea01 = ea[3 * ej0 + 1], ea02 = ea[3 * ej0 + 2];
        const float ea10 = ea[3 * ej1], ea11 = ea[3 * ej1 + 1], ea12 = ea[3 * ej1 + 2];
        const float4 xa0 = *(const float4*)(x + (size_t)(unsigned)src0 * 8);
        const float4 xb0 = *(const float4*)(x + (size_t)(unsigned)src0 * 8 + 4);
        const float4 xa1 = *(const float4*)(x + (size_t)(unsigned)src1 * 8);
        const float4 xb1 = *(const float4*)(x + (size_t)(unsigned)src1 * 8 + 4);
        const float xr0[8] = {xa0.x, xa0.y, xa0.z, xa0.w, xb0.x, xb0.y, xb0.z, xb0.w};
        const float xr1[8] = {xa1.x, xa1.y, xa1.z, xa1.w, xb1.x, xb1.y, xb1.z, xb1.w};

        float h0[8], h1[8];
#pragma unroll
        for (int t2 = 0; t2 < 8; ++t2) {
            const float z0 = b1r[t2] + ea00 * w10[t2] + ea01 * w11[t2] + ea02 * w12[t2];
            const float z1 = b1r[t2] + ea10 * w10[t2] + ea11 * w11[t2] + ea12 * w12[t2];
            h0[t2] = z0 > 0.f ? z0 : 0.f;
            h1[t2] = z1 > 0.f ? z1 : 0.f;
        }

        f32x4 a00 = {0.f, 0.f, 0.f, 0.f};
        f32x4 a01 = {0.f, 0.f, 0.f, 0.f};
        f32x4 a10 = {0.f, 0.f, 0.f, 0.f};
        f32x4 a11 = {0.f, 0.f, 0.f, 0.f};

        // ---- kk=8 bias rows first (A = pk(x), h==1; B zero except q==0) ----
        {
            union { short8 v; unsigned u[4]; } id0, id1;
#pragma unroll
            for (int p = 0; p < 4; ++p) {
                id0.u[p] = cvt_pk_bf16(xr0[2 * p], xr0[2 * p + 1]);
                id1.u[p] = cvt_pk_bf16(xr1[2 * p], xr1[2 * p + 1]);
            }
            const short8 bf0 = *(const short8*)&lds_b[(16 * 64 + lane) * 8];
            const short8 bf1 = *(const short8*)&lds_b[(17 * 64 + lane) * 8];
            a00 = __builtin_amdgcn_mfma_f32_16x16x32_bf16(id0.v, bf0, a00, 0, 0, 0);
            a01 = __builtin_amdgcn_mfma_f32_16x16x32_bf16(id0.v, bf1, a01, 0, 0, 0);
            a10 = __builtin_amdgcn_mfma_f32_16x16x32_bf16(id1.v, bf0, a10, 0, 0, 0);
            a11 = __builtin_amdgcn_mfma_f32_16x16x32_bf16(id1.v, bf1, a11, 0, 0, 0);
        }

        // ---- main K loop: B-frags shared by both groups ----
#pragma unroll
        for (int kk = 0; kk < 8; ++kk) {
            const short8 bf0 = *(const short8*)&lds_b[((kk * 2 + 0) * 64 + lane) * 8];
            const short8 bf1 = *(const short8*)&lds_b[((kk * 2 + 1) * 64 + lane) * 8];
            const float hk0 = h0[kk], hk1 = h1[kk];
            union { short8 v; unsigned u[4]; } af0, af1;
#pragma unroll
            for (int p = 0; p < 4; ++p) {
                af0.u[p] = cvt_pk_bf16(hk0 * xr0[2 * p], hk0 * xr0[2 * p + 1]);
                af1.u[p] = cvt_pk_bf16(hk1 * xr1[2 * p], hk1 * xr1[2 * p + 1]);
            }
            a00 = __builtin_amdgcn_mfma_f32_16x16x32_bf16(af0.v, bf0, a00, 0, 0, 0);
            a01 = __builtin_amdgcn_mfma_f32_16x16x32_bf16(af0.v, bf1, a01, 0, 0, 0);
            a10 = __builtin_amdgcn_mfma_f32_16x16x32_bf16(af1.v, bf0, a10, 0, 0, 0);
            a11 = __builtin_amdgcn_mfma_f32_16x16x32_bf16(af1.v, bf1, a11, 0, 0, 0);
        }

        // ---- scatter: C row m = q*4+r (edge base+m), col = e_l (o_local) ----
#pragma unroll
        for (int r = 0; r < 4; ++r) {
            const int m   = q * 4 + r;
            const int dr0 = __shfl(dst0, m, 16);   // dst held by lane with e_l==m
            const int dr1 = __shfl(dst1, m, 16);
            if (base0 + m < E) {
                atomicAdd(&s[(size_t)(unsigned)dr0 * 32 + e_l],      a00[r]);
                atomicAdd(&s[(size_t)(unsigned)dr0 * 32 + 16 + e_l], a01[r]);
            }
            if (v1 && base1 + m < E) {
                atomicAdd(&s[(size_t)(unsigned)dr1 * 32 + e_l],      a10[r]);
                atomicAdd(&s[(size_t)(unsigned)dr1 * 32 + 16 + e_l], a11[r]);
            }
        }
        if (lane < 16) {
            if (base0 + e_l < E)       atomicAdd(&cnt[dst0], 1);
            if (v1 && base1 + e_l < E) atomicAdd(&cnt[dst1], 1);
        }
    }
}

// ---- phase: node transform + partial pool ---------------------------------
static __device__ __forceinline__ void node_phase(float* red,
                                                  const float* __restrict__ s,
                                                  const int* __restrict__ cnt,
                                                  const float* __restrict__ x,
                                                  const float* __restrict__ root,
                                                  const float* __restrict__ conv_bias,
                                                  const int* __restrict__ batch,
                                                  float* __restrict__ gsum, int N)
{
    const int t    = threadIdx.x;
    const int o    = t & 31;
    const int slot = t >> 5;

    float rootr[8];
#pragma unroll
    for (int i = 0; i < 8; ++i) rootr[i] = root[i * 32 + o];
    const float cb = conv_bias[o];

    for (int base = blockIdx.x * 8; base < N; base += gridDim.x * 8) {
        __syncthreads();   // protect red[] reuse across iterations (uniform)
        const int n = base + slot;

        float v = 0.f;
        int   b = 0;
        if (n < N) {
            b = batch[n];
            const int   c    = cnt[n];
            const float rinv = 1.f / (float)(c > 1 ? c : 1);
            const float* xp  = x + (size_t)n * 8;
            float xv[8];
#pragma unroll
            for (int i = 0; i < 8; ++i) xv[i] = xp[i];
            const float t2 = s[(size_t)n * 32 + o] * rinv + cb + DOT8(xv, rootr);
            v = t2 > 0.f ? t2 : 0.f;
        }

        const int nlast  = (base + 7 < N) ? base + 7 : N - 1;
        const int bfirst = batch[base];
        const int blast  = batch[nlast];

        if (bfirst == blast && base + 7 < N) {      // block-uniform condition
            red[t] = v;
            __syncthreads();
            if (t < 32) {
                float p = 0.f;
#pragma unroll
                for (int c2 = 0; c2 < 8; ++c2) p += red[t + 32 * c2];
                atomicAdd(&gsum[bfirst * 32 + t], p);
            }
        } else {
            if (n < N) atomicAdd(&gsum[b * 32 + o], v);
        }
    }
}

// ---- phase: MLP head (one graph per block; works for 128 or 256 threads) --
static __device__ __forceinline__ void mlp_phase(float* lds,
                                                 const float* __restrict__ gsum,
                                                 const int* __restrict__ batch,
                                                 const float* __restrict__ ratios,
                                                 const int* __restrict__ ids,
                                                 const float* __restrict__ emb,
                                                 const float* __restrict__ fc0w, const float* __restrict__ fc0b,
                                                 const float* __restrict__ fc1w, const float* __restrict__ fc1b,
                                                 const float* __restrict__ fc2w, const float* __restrict__ fc2b,
                                                 float* __restrict__ out, int N, int G)
{
    if (blockIdx.x >= (unsigned)G) return;          // block-uniform

    float* zs = lds;          // [96]
    float* z1 = lds + 96;     // [64]
    float* z2 = lds + 160;    // [32]
    int*   seg = (int*)(lds + 192); // [2]

    const int g = blockIdx.x;
    const int t = threadIdx.x;

    if (t < 2) {
        const int target = g + t;
        int lo = 0, hi = N;
        while (lo < hi) {
            const int mid = (lo + hi) >> 1;
            if (batch[mid] < target) lo = mid + 1; else hi = mid;
        }
        seg[t] = lo;
    }
    __syncthreads();

    float c = (float)(seg[1] - seg[0]);
    if (c < 1.f) c = 1.f;

    if (t < 32) zs[t] = gsum[g * 32 + t] / c;
    if (t >= 32 && t < 96) {
        const int j = t - 32;
        float u = 0.f;
#pragma unroll
        for (int r = 0; r < 5; ++r) u += ratios[r] * emb[(size_t)ids[r] * 64 + j];
        zs[32 + j] = u;
    }
    __syncthreads();

    if (t < 64) {
        float a = fc0b[t];
        for (int k = 0; k < 96; ++k) a += zs[k] * fc0w[k * 64 + t];
        z1[t] = a > 0.f ? a : 0.f;
    }
    __syncthreads();

    if (t < 32) {
        float a = fc1b[t];
        for (int k = 0; k < 64; ++k) a += z1[k] * fc1w[k * 32 + t];
        z2[t] = a > 0.f ? a : 0.f;
    }
    __syncthreads();

    if (t == 0) {
        float a = fc2b[0];
        for (int k = 0; k < 32; ++k) a += z2[k] * fc2w[k];
        out[g] = a;
    }
}

// ===========================================================================
// Fused cooperative kernel: edge -> node_pool -> mlp with fast grid barriers.
// Workspace zeroing (s|cnt|gsum|bar) is done by host memset before launch.
// ===========================================================================
__global__ __launch_bounds__(256, 4)
void fused_kernel(const float* __restrict__ x,
                  const float* __restrict__ ea,
                  const float* __restrict__ ratios,
                  const int* __restrict__ eidx,
                  const int* __restrict__ batch,
                  const int* __restrict__ ids,
                  const float* __restrict__ W1, const float* __restrict__ b1,
                  const float* __restrict__ W2, const float* __restrict__ b2,
                  const float* __restrict__ emb,
                  const float* __restrict__ root,
                  const float* __restrict__ conv_bias,
                  const float* __restrict__ fc0w, const float* __restrict__ fc0b,
                  const float* __restrict__ fc1w, const float* __restrict__ fc1b,
                  const float* __restrict__ fc2w, const float* __restrict__ fc2b,
                  float* __restrict__ s, int* __restrict__ cnt,
                  float* __restrict__ gsum, int* __restrict__ bar,
                  float* __restrict__ out,
                  int N, int E, int G)
{
    __shared__ __align__(16) short lds_b[18 * 64 * 8];
    const int nb = gridDim.x;

    // Phase 0: stage B fragments
    stage_b_frags(lds_b, W2, b2);
    __syncthreads();

    // Phase 1: edge MFMA + scatter-mean atomics
    edge_compute(lds_b, x, ea, eidx, W1, b1, s, cnt, E);
    grid_sync(bar, nb);

    // Phase 2: node transform + partial pool (reuse LDS as reduce buffer)
    node_phase((float*)lds_b, s, cnt, x, root, conv_bias, batch, gsum, N);
    grid_sync(bar, nb);

    // Phase 3: MLP head (first G blocks)
    mlp_phase((float*)lds_b, gsum, batch, ratios, ids, emb,
              fc0w, fc0b, fc1w, fc1b, fc2w, fc2b, out, N, G);
}

// ===========================================================================
// Fallback standalone kernels (R8 path, proven 272.7us) — same device funcs.
// ===========================================================================
__global__ __launch_bounds__(256, 4)
void edge_kernel(const float* __restrict__ x,
                 const float* __restrict__ ea,
                 const int* __restrict__ eidx,
                 const float* __restrict__ W1, const float* __restrict__ b1,
                 const float* __restrict__ W2, const float* __restrict__ b2,
                 float* __restrict__ s, int* __restrict__ cnt, int E)
{
    __shared__ __align__(16) short lds_b[18 * 64 * 8];
    stage_b_frags(lds_b, W2, b2);
    __syncthreads();
    edge_compute(lds_b, x, ea, eidx, W1, b1, s, cnt, E);
}

__global__ __launch_bounds__(256)
void node_pool_kernel(const float* __restrict__ s,
                      const int* __restrict__ cnt,
                      const float* __restrict__ x,
                      const float* __restrict__ root,
                      const float* __restrict__ conv_bias,
                      const int* __restrict__ batch,
                      float* __restrict__ gsum, int N)
{
    __shared__ float red[256];
    node_phase(red, s, cnt, x, root, conv_bias, batch, gsum, N);
}

__global__ __launch_bounds__(128)
void mlp_kernel(const float* __restrict__ gsum,
                const int* __restrict__ batch,
                const float* __restrict__ ratios,
                const int* __restrict__ ids,
                const float* __restrict__ emb,
                const float* __restrict__ fc0w, const float* __restrict__ fc0b,
                const float* __restrict__ fc1w, const float* __restrict__ fc1b,
                const float* __restrict__ fc2w, const float* __restrict__ fc2b,
                float* __restrict__ out, int N, int G)
{
    __shared__ float lds[194];
    mlp_phase(lds, gsum, batch, ratios, ids, emb,
              fc0w, fc0b, fc1w, fc1b, fc2w, fc2b, out, N, G);
}

// ---------------------------------------------------------------------------
extern "C" void kernel_launch(void* const* d_in, const int* in_sizes, int n_in,
                              void* d_out, int out_size, void* d_ws, size_t ws_size,
                              hipStream_t stream)
{
    const float* x         = (const float*)d_in[0];
    const float* ea        = (const float*)d_in[1];
    const float* ratios    = (const float*)d_in[2];
    const int*   eidx      = (const int*)  d_in[3];
    const int*   batch     = (const int*)  d_in[4];
    const int*   ids       = (const int*)  d_in[5];
    const float* W1        = (const float*)d_in[6];
    const float* b1        = (const float*)d_in[7];
    const float* W2        = (const float*)d_in[8];
    const float* b2        = (const float*)d_in[9];
    const float* emb       = (const float*)d_in[10];
    const float* root      = (const float*)d_in[11];
    const float* conv_bias = (const float*)d_in[12];
    const float* fc0w      = (const float*)d_in[13];
    const float* fc0b      = (const float*)d_in[14];
    const float* fc1w      = (const float*)d_in[15];
    const float* fc1b      = (const float*)d_in[16];
    const float* fc2w      = (const float*)d_in[17];
    const float* fc2b      = (const float*)d_in[18];

    int N = in_sizes[0] / NODE_DIM;   // 50000
    int E = in_sizes[1] / 3;          // 1000000
    int G = out_size;                 // 128

    // Workspace: s f32[N,32] | cnt int[N] | gsum f32[G,32] | bar int[2]
    float* s    = (float*)d_ws;
    int*   cnt  = (int*)((char*)d_ws + (size_t)N * 32 * 4);
    float* gsum = (float*)((char*)d_ws + (size_t)N * 32 * 4 + (size_t)N * 4);
    int*   bar  = (int*)((char*)d_ws + (size_t)N * 32 * 4 + (size_t)N * 4
                                     + (size_t)G * 32 * 4);
    float* outp = (float*)d_out;

    const size_t zbytes = (size_t)N * 32 * 4 + (size_t)N * 4
                        + (size_t)G * 32 * 4 + 2 * 4;
    (void)hipMemsetAsync(d_ws, 0, zbytes, stream);

    // ---- fused cooperative path (1 compute dispatch) ----
    void* kargs[] = {
        (void*)&x, (void*)&ea, (void*)&ratios, (void*)&eidx, (void*)&batch,
        (void*)&ids, (void*)&W1, (void*)&b1, (void*)&W2, (void*)&b2,
        (void*)&emb, (void*)&root, (void*)&conv_bias,
        (void*)&fc0w, (void*)&fc0b, (void*)&fc1w, (void*)&fc1b,
        (void*)&fc2w, (void*)&fc2b,
        (void*)&s, (void*)&cnt, (void*)&gsum, (void*)&bar, (void*)&outp,
        (void*)&N, (void*)&E, (void*)&G
    };
    hipError_t err = hipLaunchCooperativeKernel((const void*)fused_kernel,
                                                dim3(1024), dim3(256),
                                                kargs, 0, stream);
    if (err == hipSuccess) return;

    // ---- fallback: proven R8 3-kernel path ----
    (void)hipGetLastError();   // clear sticky error
    edge_kernel<<<2048, 256, 0, stream>>>(x, ea, eidx, W1, b1, W2, b2, s, cnt, E);
    node_pool_kernel<<<(N + 7) / 8, 256, 0, stream>>>(s, cnt, x, root, conv_bias,
                                                      batch, gsum, N);
    mlp_kernel<<<G, 128, 0, stream>>>(gsum, batch, ratios, ids, emb,
                                      fc0w, fc0b, fc1w, fc1b, fc2w, fc2b,
                                      outp, N, G);
}

// Round 9
// 278.183 us; speedup vs baseline: 2.9499x; 2.9499x over previous
//
#include <hip/hip_runtime.h>

#define NODE_DIM 8

typedef __attribute__((ext_vector_type(8))) short short8;
typedef __attribute__((ext_vector_type(4))) float f32x4;

// 8-term dot; param must not be named w/x/y/z (macro hits member access).
#define DOT8(xv, WT) ((xv)[0]*(WT)[0] + (xv)[1]*(WT)[1] + (xv)[2]*(WT)[2] + (xv)[3]*(WT)[3] + \
                      (xv)[4]*(WT)[4] + (xv)[5]*(WT)[5] + (xv)[6]*(WT)[6] + (xv)[7]*(WT)[7])

// Single-instruction RNE fp32 pair -> packed bf16x2 (a -> low16, b -> high16).
static __device__ __forceinline__ unsigned cvt_pk_bf16(float a, float b) {
    unsigned r;
    asm("v_cvt_pk_bf16_f32 %0, %1, %2" : "=v"(r) : "v"(a), "v"(b));
    return r;
}

// ===========================================================================
// R13: dispatch-count reduction WITHOUT cooperative launch. Evidence:
//   - regular dispatch overhead ~25us each (R2 gap 100/4, R10 gap 218/8)
//   - hipLaunchCooperativeKernel adds ~100us launch overhead by itself
//     (R11/R12 gaps ~110us at 2 dispatches) -> fusion via coop is dead.
// Fix: node_pool + mlp fuse into ONE regular kernel with NO grid sync:
// batch is sorted, so block g binary-searches its node segment, pools its
// own graph's nodes block-locally, then runs the MLP for graph g.
// Eliminates: mlp dispatch, gsum buffer + its atomics + its zeroing.
// 3 dispatches total: memset(s,cnt) + edge (R8, unchanged) + node_mlp.
// ===========================================================================

// ---- stage B fragments (bf16, frag-order) into LDS ------------------------
static __device__ __forceinline__ void stage_b_frags(short* lds_b,
                                                     const float* __restrict__ W2,
                                                     const float* __restrict__ b2)
{
    const int t = threadIdx.x;
    for (int f = t; f < 18 * 64 * 8; f += 256) {
        const int j   = f & 7;
        const int ln  = (f >> 3) & 63;
        const int fid = f >> 9;            // 0..17
        const int kk  = fid >> 1, ot = fid & 1;
        const int qq  = ln >> 4, ol = ln & 15;
        float v;
        if (kk < 8) v = W2[(kk * 4 + qq) * 256 + j * 32 + ot * 16 + ol];
        else        v = (qq == 0) ? b2[j * 32 + ot * 16 + ol] : 0.f;
        unsigned uv = __float_as_uint(v);
        uv = (uv + 0x7fffu + ((uv >> 16) & 1u)) >> 16;
        lds_b[f] = (short)uv;
    }
}

// ---- edge MFMA + scatter-mean atomics (R8 logic, proven @272.7us) ---------
static __device__ __forceinline__ void edge_compute(const short* lds_b,
                                                    const float* __restrict__ x,
                                                    const float* __restrict__ ea,
                                                    const int* __restrict__ eidx,
                                                    const float* __restrict__ W1,
                                                    const float* __restrict__ b1,
                                                    float* __restrict__ s,
                                                    int* __restrict__ cnt,
                                                    int E)
{
    const int t    = threadIdx.x;
    const int lane = t & 63;
    const int e_l  = lane & 15;    // edge slot within group (A: m, C: n!)
    const int q    = lane >> 4;    // quad

    // W1 columns for this lane's h set: k = 4t+q.
    float w10[8], w11[8], w12[8], b1r[8];
#pragma unroll
    for (int t2 = 0; t2 < 8; ++t2) {
        const int k = 4 * t2 + q;
        w10[t2] = W1[k]; w11[t2] = W1[32 + k]; w12[t2] = W1[64 + k]; b1r[t2] = b1[k];
    }

    const int wave = blockIdx.x * 4 + (t >> 6);
    const int nwav = gridDim.x * 4;
    const int ngrp = (E + 15) / 16;

    for (int g0 = 2 * wave; g0 < ngrp; g0 += 2 * nwav) {
        const bool v1    = (g0 + 1) < ngrp;
        const int  base0 = g0 * 16;
        const int  base1 = (v1 ? g0 + 1 : g0) * 16;

        int ej0 = base0 + e_l; if (ej0 >= E) ej0 = E - 1;
        int ej1 = base1 + e_l; if (ej1 >= E) ej1 = E - 1;

        // ---- all global loads for both groups issued up front ----
        const int src0 = eidx[ej0];
        const int dst0 = eidx[E + ej0];
        const int src1 = eidx[ej1];
        const int dst1 = eidx[E + ej1];
        const float ea00 = ea[3 * ej0], ea01 = ea[3 * ej0 + 1], ea02 = ea[3 * ej0 + 2];
        const float ea10 = ea[3 * ej1], ea11 = ea[3 * ej1 + 1], ea12 = ea[3 * ej1 + 2];
        const float4 xa0 = *(const float4*)(x + (size_t)(unsigned)src0 * 8);
        const float4 xb0 = *(const float4*)(x + (size_t)(unsigned)src0 * 8 + 4);
        const float4 xa1 = *(const float4*)(x + (size_t)(unsigned)src1 * 8);
        const float4 xb1 = *(const float4*)(x + (size_t)(unsigned)src1 * 8 + 4);
        const float xr0[8] = {xa0.x, xa0.y, xa0.z, xa0.w, xb0.x, xb0.y, xb0.z, xb0.w};
        const float xr1[8] = {xa1.x, xa1.y, xa1.z, xa1.w, xb1.x, xb1.y, xb1.z, xb1.w};

        float h0[8], h1[8];
#pragma unroll
        for (int t2 = 0; t2 < 8; ++t2) {
            const float z0 = b1r[t2] + ea00 * w10[t2] + ea01 * w11[t2] + ea02 * w12[t2];
            const float z1 = b1r[t2] + ea10 * w10[t2] + ea11 * w11[t2] + ea12 * w12[t2];
            h0[t2] = z0 > 0.f ? z0 : 0.f;
            h1[t2] = z1 > 0.f ? z1 : 0.f;
        }

        f32x4 a00 = {0.f, 0.f, 0.f, 0.f};
        f32x4 a01 = {0.f, 0.f, 0.f, 0.f};
        f32x4 a10 = {0.f, 0.f, 0.f, 0.f};
        f32x4 a11 = {0.f, 0.f, 0.f, 0.f};

        // ---- kk=8 bias rows first (A = pk(x), h==1; B zero except q==0) ----
        {
            union { short8 v; unsigned u[4]; } id0, id1;
#pragma unroll
            for (int p = 0; p < 4; ++p) {
                id0.u[p] = cvt_pk_bf16(xr0[2 * p], xr0[2 * p + 1]);
                id1.u[p] = cvt_pk_bf16(xr1[2 * p], xr1[2 * p + 1]);
            }
            const short8 bf0 = *(const short8*)&lds_b[(16 * 64 + lane) * 8];
            const short8 bf1 = *(const short8*)&lds_b[(17 * 64 + lane) * 8];
            a00 = __builtin_amdgcn_mfma_f32_16x16x32_bf16(id0.v, bf0, a00, 0, 0, 0);
            a01 = __builtin_amdgcn_mfma_f32_16x16x32_bf16(id0.v, bf1, a01, 0, 0, 0);
            a10 = __builtin_amdgcn_mfma_f32_16x16x32_bf16(id1.v, bf0, a10, 0, 0, 0);
            a11 = __builtin_amdgcn_mfma_f32_16x16x32_bf16(id1.v, bf1, a11, 0, 0, 0);
        }

        // ---- main K loop: B-frags shared by both groups ----
#pragma unroll
        for (int kk = 0; kk < 8; ++kk) {
            const short8 bf0 = *(const short8*)&lds_b[((kk * 2 + 0) * 64 + lane) * 8];
            const short8 bf1 = *(const short8*)&lds_b[((kk * 2 + 1) * 64 + lane) * 8];
            const float hk0 = h0[kk], hk1 = h1[kk];
            union { short8 v; unsigned u[4]; } af0, af1;
#pragma unroll
            for (int p = 0; p < 4; ++p) {
                af0.u[p] = cvt_pk_bf16(hk0 * xr0[2 * p], hk0 * xr0[2 * p + 1]);
                af1.u[p] = cvt_pk_bf16(hk1 * xr1[2 * p], hk1 * xr1[2 * p + 1]);
            }
            a00 = __builtin_amdgcn_mfma_f32_16x16x32_bf16(af0.v, bf0, a00, 0, 0, 0);
            a01 = __builtin_amdgcn_mfma_f32_16x16x32_bf16(af0.v, bf1, a01, 0, 0, 0);
            a10 = __builtin_amdgcn_mfma_f32_16x16x32_bf16(af1.v, bf0, a10, 0, 0, 0);
            a11 = __builtin_amdgcn_mfma_f32_16x16x32_bf16(af1.v, bf1, a11, 0, 0, 0);
        }

        // ---- scatter: C row m = q*4+r (edge base+m), col = e_l (o_local) ----
#pragma unroll
        for (int r = 0; r < 4; ++r) {
            const int m   = q * 4 + r;
            const int dr0 = __shfl(dst0, m, 16);   // dst held by lane with e_l==m
            const int dr1 = __shfl(dst1, m, 16);
            if (base0 + m < E) {
                atomicAdd(&s[(size_t)(unsigned)dr0 * 32 + e_l],      a00[r]);
                atomicAdd(&s[(size_t)(unsigned)dr0 * 32 + 16 + e_l], a01[r]);
            }
            if (v1 && base1 + m < E) {
                atomicAdd(&s[(size_t)(unsigned)dr1 * 32 + e_l],      a10[r]);
                atomicAdd(&s[(size_t)(unsigned)dr1 * 32 + 16 + e_l], a11[r]);
            }
        }
        if (lane < 16) {
            if (base0 + e_l < E)       atomicAdd(&cnt[dst0], 1);
            if (v1 && base1 + e_l < E) atomicAdd(&cnt[dst1], 1);
        }
    }
}

__global__ __launch_bounds__(256, 4)
void edge_kernel(const float* __restrict__ x,
                 const float* __restrict__ ea,
                 const int* __restrict__ eidx,
                 const float* __restrict__ W1, const float* __restrict__ b1,
                 const float* __restrict__ W2, const float* __restrict__ b2,
                 float* __restrict__ s, int* __restrict__ cnt, int E)
{
    __shared__ __align__(16) short lds_b[18 * 64 * 8];
    stage_b_frags(lds_b, W2, b2);
    __syncthreads();
    edge_compute(lds_b, x, ea, eidx, W1, b1, s, cnt, E);
}

// ===========================================================================
// node_mlp_kernel: one 256-thread block per GRAPH. batch is sorted, so block
// g owns nodes [seg0, seg1): it does the node transform + ReLU + pool for its
// own nodes block-locally (no gsum, no atomics), then runs the 3-layer MLP.
// Replaces node_pool_kernel + mlp_kernel (saves one dispatch ~25us + gsum).
// ===========================================================================
__global__ __launch_bounds__(256)
void node_mlp_kernel(const float* __restrict__ s,
                     const int* __restrict__ cnt,
                     const float* __restrict__ x,
                     const float* __restrict__ root,
                     const float* __restrict__ conv_bias,
                     const int* __restrict__ batch,
                     const float* __restrict__ ratios,
                     const int* __restrict__ ids,
                     const float* __restrict__ emb,
                     const float* __restrict__ fc0w, const float* __restrict__ fc0b,
                     const float* __restrict__ fc1w, const float* __restrict__ fc1b,
                     const float* __restrict__ fc2w, const float* __restrict__ fc2b,
                     float* __restrict__ out, int N)
{
    __shared__ float red[256];
    __shared__ float zs[96];
    __shared__ float z1[64];
    __shared__ float z2[32];
    __shared__ int   seg[2];

    const int g    = blockIdx.x;
    const int t    = threadIdx.x;
    const int o    = t & 31;     // output channel
    const int slot = t >> 5;     // node slot (8 nodes in flight)

    // segment [seg0, seg1) of this graph's nodes
    if (t < 2) {
        const int target = g + t;
        int lo = 0, hi = N;
        while (lo < hi) {
            const int mid = (lo + hi) >> 1;
            if (batch[mid] < target) lo = mid + 1; else hi = mid;
        }
        seg[t] = lo;
    }
    __syncthreads();
    const int s0 = seg[0], s1 = seg[1];

    float rootr[8];
#pragma unroll
    for (int i = 0; i < 8; ++i) rootr[i] = root[i * 32 + o];
    const float cb = conv_bias[o];

    // node transform + ReLU + local pool over this graph's nodes
    float acc = 0.f;
    for (int n = s0 + slot; n < s1; n += 8) {
        const int   c    = cnt[n];
        const float rinv = 1.f / (float)(c > 1 ? c : 1);
        const float* xp  = x + (size_t)n * 8;
        float xv[8];
#pragma unroll
        for (int i = 0; i < 8; ++i) xv[i] = xp[i];
        const float t2 = s[(size_t)n * 32 + o] * rinv + cb + DOT8(xv, rootr);
        acc += t2 > 0.f ? t2 : 0.f;
    }
    red[t] = acc;
    __syncthreads();

    // pooled mean -> zs[0:32]; weighted element embedding -> zs[32:96]
    if (t < 32) {
        float p = 0.f;
#pragma unroll
        for (int c2 = 0; c2 < 8; ++c2) p += red[t + 32 * c2];
        float c = (float)(s1 - s0);
        if (c < 1.f) c = 1.f;
        zs[t] = p / c;
    }
    if (t >= 32 && t < 96) {
        const int j = t - 32;
        float u = 0.f;
#pragma unroll
        for (int r = 0; r < 5; ++r) u += ratios[r] * emb[(size_t)ids[r] * 64 + j];
        zs[32 + j] = u;
    }
    __syncthreads();

    if (t < 64) {
        float a = fc0b[t];
        for (int k = 0; k < 96; ++k) a += zs[k] * fc0w[k * 64 + t];
        z1[t] = a > 0.f ? a : 0.f;
    }
    __syncthreads();

    if (t < 32) {
        float a = fc1b[t];
        for (int k = 0; k < 64; ++k) a += z1[k] * fc1w[k * 32 + t];
        z2[t] = a > 0.f ? a : 0.f;
    }
    __syncthreads();

    if (t == 0) {
        float a = fc2b[0];
        for (int k = 0; k < 32; ++k) a += z2[k] * fc2w[k];
        out[g] = a;
    }
}

// ---------------------------------------------------------------------------
extern "C" void kernel_launch(void* const* d_in, const int* in_sizes, int n_in,
                              void* d_out, int out_size, void* d_ws, size_t ws_size,
                              hipStream_t stream)
{
    const float* x         = (const float*)d_in[0];
    const float* ea        = (const float*)d_in[1];
    const float* ratios    = (const float*)d_in[2];
    const int*   eidx      = (const int*)  d_in[3];
    const int*   batch     = (const int*)  d_in[4];
    const int*   ids       = (const int*)  d_in[5];
    const float* W1        = (const float*)d_in[6];
    const float* b1        = (const float*)d_in[7];
    const float* W2        = (const float*)d_in[8];
    const float* b2        = (const float*)d_in[9];
    const float* emb       = (const float*)d_in[10];
    const float* root      = (const float*)d_in[11];
    const float* conv_bias = (const float*)d_in[12];
    const float* fc0w      = (const float*)d_in[13];
    const float* fc0b      = (const float*)d_in[14];
    const float* fc1w      = (const float*)d_in[15];
    const float* fc1b      = (const float*)d_in[16];
    const float* fc2w      = (const float*)d_in[17];
    const float* fc2b      = (const float*)d_in[18];

    const int N = in_sizes[0] / NODE_DIM;   // 50000
    const int E = in_sizes[1] / 3;          // 1000000
    const int G = out_size;                 // 128

    // Workspace: s f32[N,32] | cnt int[N]
    float* s   = (float*)d_ws;
    int*   cnt = (int*)((char*)d_ws + (size_t)N * 32 * 4);

    (void)hipMemsetAsync(d_ws, 0, (size_t)N * 32 * 4 + (size_t)N * 4, stream);

    edge_kernel<<<2048, 256, 0, stream>>>(x, ea, eidx, W1, b1, W2, b2, s, cnt, E);
    node_mlp_kernel<<<G, 256, 0, stream>>>(s, cnt, x, root, conv_bias, batch,
                                           ratios, ids, emb,
                                           fc0w, fc0b, fc1w, fc1b, fc2w, fc2b,
                                           (float*)d_out, N);
}

// Round 10
// 276.391 us; speedup vs baseline: 2.9690x; 1.0065x over previous
//
#include <hip/hip_runtime.h>

#define NODE_DIM 8

typedef __attribute__((ext_vector_type(8))) short short8;
typedef __attribute__((ext_vector_type(4))) float f32x4;

// 8-term dot; param must not be named w/x/y/z (macro hits member access).
#define DOT8(xv, WT) ((xv)[0]*(WT)[0] + (xv)[1]*(WT)[1] + (xv)[2]*(WT)[2] + (xv)[3]*(WT)[3] + \
                      (xv)[4]*(WT)[4] + (xv)[5]*(WT)[5] + (xv)[6]*(WT)[6] + (xv)[7]*(WT)[7])

// Single-instruction RNE fp32 pair -> packed bf16x2 (a -> low16, b -> high16).
static __device__ __forceinline__ unsigned cvt_pk_bf16(float a, float b) {
    unsigned r;
    asm("v_cvt_pk_bf16_f32 %0, %1, %2" : "=v"(r) : "v"(a), "v"(b));
    return r;
}

// ===========================================================================
// R14: atomic OP-vs-BYTE diagnostic + likely win. Ledger: edge kernel pinned
// at 33e6 atomic dwords / 162us = 204 G RMW/s across R7/R8/R13, invariant to
// VALU/occupancy/read changes. R9 (pk f16) would have halved ops+bytes but
// failed precision (16-bit RUNNING SUM). Fix that flaw with FIXED-POINT:
// pack channels (2j,2j+1) as two 32-bit fields in one u64:
//     field = (int)rint(v * 2^15) + 2^21   (non-negative: |v|<64 >> |msg|~5)
// u64 atomicAdd merges both fields; no borrow/carry crosses the boundary
// (deg<~100 -> field sum < 2^28). Decode: ((int)(field - cnt*2^21)) / 2^15.
// Quantization ~1.5e-5/term -> ~3e-6 at h_node, under bf16-MFMA noise.
// 16 u64 atomics/edge replace 32 f32: ops halve, bytes constant.
//   op-bound  -> edge ~162 -> ~95-110us (predicted)
//   byte-bound-> unchanged -> f32 atomic traffic is irreducible = roofline.
// Everything else identical to R13 (278.2us proven): R8 edge structure,
// fused node_mlp, fixed ~100us replay overhead out of reach.
// ===========================================================================

#define FIX_SCALE 32768.0f          // 2^15
#define FIX_BIAS  (1u << 21)        // per-contribution bias, subtracted via cnt

static __device__ __forceinline__ unsigned fix_enc(float v) {
    return (unsigned)((int)rintf(v * FIX_SCALE) + (int)FIX_BIAS);
}

// ---- stage B fragments (bf16, frag-order) into LDS ------------------------
static __device__ __forceinline__ void stage_b_frags(short* lds_b,
                                                     const float* __restrict__ W2,
                                                     const float* __restrict__ b2)
{
    const int t = threadIdx.x;
    for (int f = t; f < 18 * 64 * 8; f += 256) {
        const int j   = f & 7;
        const int ln  = (f >> 3) & 63;
        const int fid = f >> 9;            // 0..17
        const int kk  = fid >> 1, ot = fid & 1;
        const int qq  = ln >> 4, ol = ln & 15;
        float v;
        if (kk < 8) v = W2[(kk * 4 + qq) * 256 + j * 32 + ot * 16 + ol];
        else        v = (qq == 0) ? b2[j * 32 + ot * 16 + ol] : 0.f;
        unsigned uv = __float_as_uint(v);
        uv = (uv + 0x7fffu + ((uv >> 16) & 1u)) >> 16;
        lds_b[f] = (short)uv;
    }
}

// ---- edge MFMA + packed fixed-point u64 atomics ---------------------------
static __device__ __forceinline__ void edge_compute(const short* lds_b,
                                                    const float* __restrict__ x,
                                                    const float* __restrict__ ea,
                                                    const int* __restrict__ eidx,
                                                    const float* __restrict__ W1,
                                                    const float* __restrict__ b1,
                                                    unsigned long long* __restrict__ s,
                                                    int* __restrict__ cnt,
                                                    int E)
{
    const int t    = threadIdx.x;
    const int lane = t & 63;
    const int e_l  = lane & 15;    // edge slot within group (A: m, C: n!)
    const int q    = lane >> 4;    // quad

    // W1 columns for this lane's h set: k = 4t+q.
    float w10[8], w11[8], w12[8], b1r[8];
#pragma unroll
    for (int t2 = 0; t2 < 8; ++t2) {
        const int k = 4 * t2 + q;
        w10[t2] = W1[k]; w11[t2] = W1[32 + k]; w12[t2] = W1[64 + k]; b1r[t2] = b1[k];
    }

    const int wave = blockIdx.x * 4 + (t >> 6);
    const int nwav = gridDim.x * 4;
    const int ngrp = (E + 15) / 16;

    // u64 qword index within a row for this lane's channel pair:
    //   even e_l: channels (e_l, e_l+1)        -> qw = e_l/2        (0..7)
    //   odd  e_l: channels (16+e_l-1, 16+e_l)  -> qw = 8 + e_l/2    (8..15)
    const bool ev = (e_l & 1) == 0;
    const int  qw = ev ? (e_l >> 1) : (8 + (e_l >> 1));

    for (int g0 = 2 * wave; g0 < ngrp; g0 += 2 * nwav) {
        const bool v1    = (g0 + 1) < ngrp;
        const int  base0 = g0 * 16;
        const int  base1 = (v1 ? g0 + 1 : g0) * 16;

        int ej0 = base0 + e_l; if (ej0 >= E) ej0 = E - 1;
        int ej1 = base1 + e_l; if (ej1 >= E) ej1 = E - 1;

        // ---- all global loads for both groups issued up front ----
        const int src0 = eidx[ej0];
        const int dst0 = eidx[E + ej0];
        const int src1 = eidx[ej1];
        const int dst1 = eidx[E + ej1];
        const float ea00 = ea[3 * ej0], ea01 = ea[3 * ej0 + 1], ea02 = ea[3 * ej0 + 2];
        const float ea10 = ea[3 * ej1], ea11 = ea[3 * ej1 + 1], ea12 = ea[3 * ej1 + 2];
        const float4 xa0 = *(const float4*)(x + (size_t)(unsigned)src0 * 8);
        const float4 xb0 = *(const float4*)(x + (size_t)(unsigned)src0 * 8 + 4);
        const float4 xa1 = *(const float4*)(x + (size_t)(unsigned)src1 * 8);
        const float4 xb1 = *(const float4*)(x + (size_t)(unsigned)src1 * 8 + 4);
        const float xr0[8] = {xa0.x, xa0.y, xa0.z, xa0.w, xb0.x, xb0.y, xb0.z, xb0.w};
        const float xr1[8] = {xa1.x, xa1.y, xa1.z, xa1.w, xb1.x, xb1.y, xb1.z, xb1.w};

        float h0[8], h1[8];
#pragma unroll
        for (int t2 = 0; t2 < 8; ++t2) {
            const float z0 = b1r[t2] + ea00 * w10[t2] + ea01 * w11[t2] + ea02 * w12[t2];
            const float z1 = b1r[t2] + ea10 * w10[t2] + ea11 * w11[t2] + ea12 * w12[t2];
            h0[t2] = z0 > 0.f ? z0 : 0.f;
            h1[t2] = z1 > 0.f ? z1 : 0.f;
        }

        f32x4 a00 = {0.f, 0.f, 0.f, 0.f};
        f32x4 a01 = {0.f, 0.f, 0.f, 0.f};
        f32x4 a10 = {0.f, 0.f, 0.f, 0.f};
        f32x4 a11 = {0.f, 0.f, 0.f, 0.f};

        // ---- kk=8 bias rows first (A = pk(x), h==1; B zero except q==0) ----
        {
            union { short8 v; unsigned u[4]; } id0, id1;
#pragma unroll
            for (int p = 0; p < 4; ++p) {
                id0.u[p] = cvt_pk_bf16(xr0[2 * p], xr0[2 * p + 1]);
                id1.u[p] = cvt_pk_bf16(xr1[2 * p], xr1[2 * p + 1]);
            }
            const short8 bf0 = *(const short8*)&lds_b[(16 * 64 + lane) * 8];
            const short8 bf1 = *(const short8*)&lds_b[(17 * 64 + lane) * 8];
            a00 = __builtin_amdgcn_mfma_f32_16x16x32_bf16(id0.v, bf0, a00, 0, 0, 0);
            a01 = __builtin_amdgcn_mfma_f32_16x16x32_bf16(id0.v, bf1, a01, 0, 0, 0);
            a10 = __builtin_amdgcn_mfma_f32_16x16x32_bf16(id1.v, bf0, a10, 0, 0, 0);
            a11 = __builtin_amdgcn_mfma_f32_16x16x32_bf16(id1.v, bf1, a11, 0, 0, 0);
        }

        // ---- main K loop: B-frags shared by both groups ----
#pragma unroll
        for (int kk = 0; kk < 8; ++kk) {
            const short8 bf0 = *(const short8*)&lds_b[((kk * 2 + 0) * 64 + lane) * 8];
            const short8 bf1 = *(const short8*)&lds_b[((kk * 2 + 1) * 64 + lane) * 8];
            const float hk0 = h0[kk], hk1 = h1[kk];
            union { short8 v; unsigned u[4]; } af0, af1;
#pragma unroll
            for (int p = 0; p < 4; ++p) {
                af0.u[p] = cvt_pk_bf16(hk0 * xr0[2 * p], hk0 * xr0[2 * p + 1]);
                af1.u[p] = cvt_pk_bf16(hk1 * xr1[2 * p], hk1 * xr1[2 * p + 1]);
            }
            a00 = __builtin_amdgcn_mfma_f32_16x16x32_bf16(af0.v, bf0, a00, 0, 0, 0);
            a01 = __builtin_amdgcn_mfma_f32_16x16x32_bf16(af0.v, bf1, a01, 0, 0, 0);
            a10 = __builtin_amdgcn_mfma_f32_16x16x32_bf16(af1.v, bf0, a10, 0, 0, 0);
            a11 = __builtin_amdgcn_mfma_f32_16x16x32_bf16(af1.v, bf1, a11, 0, 0, 0);
        }

        // ---- scatter: one u64 fixed-point atomic per lane per C-row -------
        // Channel pair via shfl_xor(1): even lane flushes acc0 pair (e_l,e_l+1),
        // odd lane flushes acc1 pair (16+e_l-1, 16+e_l). 16 u64 atomics/edge.
#pragma unroll
        for (int r = 0; r < 4; ++r) {
            const int m   = q * 4 + r;
            const int dr0 = __shfl(dst0, m, 16);   // dst held by lane with e_l==m
            const int dr1 = __shfl(dst1, m, 16);
            const float p00 = __shfl_xor(a00[r], 1);
            const float p01 = __shfl_xor(a01[r], 1);
            const float p10 = __shfl_xor(a10[r], 1);
            const float p11 = __shfl_xor(a11[r], 1);
            unsigned lo0, hi0, lo1, hi1;
            if (ev) { lo0 = fix_enc(a00[r]); hi0 = fix_enc(p00);
                      lo1 = fix_enc(a10[r]); hi1 = fix_enc(p10); }
            else    { lo0 = fix_enc(p01);    hi0 = fix_enc(a01[r]);
                      lo1 = fix_enc(p11);    hi1 = fix_enc(a11[r]); }
            const unsigned long long val0 = (unsigned long long)lo0 |
                                            ((unsigned long long)hi0 << 32);
            const unsigned long long val1 = (unsigned long long)lo1 |
                                            ((unsigned long long)hi1 << 32);
            if (base0 + m < E)
                atomicAdd(&s[(size_t)(unsigned)dr0 * 16 + qw], val0);
            if (v1 && base1 + m < E)
                atomicAdd(&s[(size_t)(unsigned)dr1 * 16 + qw], val1);
        }
        if (lane < 16) {
            if (base0 + e_l < E)       atomicAdd(&cnt[dst0], 1);
            if (v1 && base1 + e_l < E) atomicAdd(&cnt[dst1], 1);
        }
    }
}

__global__ __launch_bounds__(256, 4)
void edge_kernel(const float* __restrict__ x,
                 const float* __restrict__ ea,
                 const int* __restrict__ eidx,
                 const float* __restrict__ W1, const float* __restrict__ b1,
                 const float* __restrict__ W2, const float* __restrict__ b2,
                 unsigned long long* __restrict__ s, int* __restrict__ cnt, int E)
{
    __shared__ __align__(16) short lds_b[18 * 64 * 8];
    stage_b_frags(lds_b, W2, b2);
    __syncthreads();
    edge_compute(lds_b, x, ea, eidx, W1, b1, s, cnt, E);
}

// ===========================================================================
// node_mlp_kernel (R13 structure): one 256-thread block per GRAPH; decodes
// the fixed-point s fields, node transform + ReLU + block-local pool + MLP.
// ===========================================================================
__global__ __launch_bounds__(256)
void node_mlp_kernel(const unsigned long long* __restrict__ s,
                     const int* __restrict__ cnt,
                     const float* __restrict__ x,
                     const float* __restrict__ root,
                     const float* __restrict__ conv_bias,
                     const int* __restrict__ batch,
                     const float* __restrict__ ratios,
                     const int* __restrict__ ids,
                     const float* __restrict__ emb,
                     const float* __restrict__ fc0w, const float* __restrict__ fc0b,
                     const float* __restrict__ fc1w, const float* __restrict__ fc1b,
                     const float* __restrict__ fc2w, const float* __restrict__ fc2b,
                     float* __restrict__ out, int N)
{
    __shared__ float red[256];
    __shared__ float zs[96];
    __shared__ float z1[64];
    __shared__ float z2[32];
    __shared__ int   seg[2];

    const int g    = blockIdx.x;
    const int t    = threadIdx.x;
    const int o    = t & 31;     // output channel
    const int slot = t >> 5;     // node slot (8 nodes in flight)

    // qword + field for this channel: ch 0..15 -> qw o/2; ch 16..31 -> 8+(o-16)/2
    const int qw  = (o < 16) ? (o >> 1) : (8 + ((o - 16) >> 1));
    const int fld = o & 1;

    // segment [seg0, seg1) of this graph's nodes
    if (t < 2) {
        const int target = g + t;
        int lo = 0, hi = N;
        while (lo < hi) {
            const int mid = (lo + hi) >> 1;
            if (batch[mid] < target) lo = mid + 1; else hi = mid;
        }
        seg[t] = lo;
    }
    __syncthreads();
    const int s0 = seg[0], s1 = seg[1];

    float rootr[8];
#pragma unroll
    for (int i = 0; i < 8; ++i) rootr[i] = root[i * 32 + o];
    const float cb = conv_bias[o];

    // node transform + ReLU + local pool over this graph's nodes
    float acc = 0.f;
    for (int n = s0 + slot; n < s1; n += 8) {
        const int   c    = cnt[n];
        const float rinv = 1.f / (float)(c > 1 ? c : 1);
        const unsigned long long w = s[(size_t)n * 16 + qw];
        const unsigned fr  = fld ? (unsigned)(w >> 32) : (unsigned)w;
        const float    sv  = (float)((int)(fr - (unsigned)c * FIX_BIAS)) / FIX_SCALE;
        const float* xp  = x + (size_t)n * 8;
        float xv[8];
#pragma unroll
        for (int i = 0; i < 8; ++i) xv[i] = xp[i];
        const float t2 = sv * rinv + cb + DOT8(xv, rootr);
        acc += t2 > 0.f ? t2 : 0.f;
    }
    red[t] = acc;
    __syncthreads();

    // pooled mean -> zs[0:32]; weighted element embedding -> zs[32:96]
    if (t < 32) {
        float p = 0.f;
#pragma unroll
        for (int c2 = 0; c2 < 8; ++c2) p += red[t + 32 * c2];
        float c = (float)(s1 - s0);
        if (c < 1.f) c = 1.f;
        zs[t] = p / c;
    }
    if (t >= 32 && t < 96) {
        const int j = t - 32;
        float u = 0.f;
#pragma unroll
        for (int r = 0; r < 5; ++r) u += ratios[r] * emb[(size_t)ids[r] * 64 + j];
        zs[32 + j] = u;
    }
    __syncthreads();

    if (t < 64) {
        float a = fc0b[t];
        for (int k = 0; k < 96; ++k) a += zs[k] * fc0w[k * 64 + t];
        z1[t] = a > 0.f ? a : 0.f;
    }
    __syncthreads();

    if (t < 32) {
        float a = fc1b[t];
        for (int k = 0; k < 64; ++k) a += z1[k] * fc1w[k * 32 + t];
        z2[t] = a > 0.f ? a : 0.f;
    }
    __syncthreads();

    if (t == 0) {
        float a = fc2b[0];
        for (int k = 0; k < 32; ++k) a += z2[k] * fc2w[k];
        out[g] = a;
    }
}

// ---------------------------------------------------------------------------
extern "C" void kernel_launch(void* const* d_in, const int* in_sizes, int n_in,
                              void* d_out, int out_size, void* d_ws, size_t ws_size,
                              hipStream_t stream)
{
    const float* x         = (const float*)d_in[0];
    const float* ea        = (const float*)d_in[1];
    const float* ratios    = (const float*)d_in[2];
    const int*   eidx      = (const int*)  d_in[3];
    const int*   batch     = (const int*)  d_in[4];
    const int*   ids       = (const int*)  d_in[5];
    const float* W1        = (const float*)d_in[6];
    const float* b1        = (const float*)d_in[7];
    const float* W2        = (const float*)d_in[8];
    const float* b2        = (const float*)d_in[9];
    const float* emb       = (const float*)d_in[10];
    const float* root      = (const float*)d_in[11];
    const float* conv_bias = (const float*)d_in[12];
    const float* fc0w      = (const float*)d_in[13];
    const float* fc0b      = (const float*)d_in[14];
    const float* fc1w      = (const float*)d_in[15];
    const float* fc1b      = (const float*)d_in[16];
    const float* fc2w      = (const float*)d_in[17];
    const float* fc2b      = (const float*)d_in[18];

    const int N = in_sizes[0] / NODE_DIM;   // 50000
    const int E = in_sizes[1] / 3;          // 1000000
    const int G = out_size;                 // 128

    // Workspace: s u64[N,16] (fixed-point packed, same bytes as f32[N,32]) | cnt int[N]
    unsigned long long* s = (unsigned long long*)d_ws;
    int* cnt = (int*)((char*)d_ws + (size_t)N * 16 * 8);

    (void)hipMemsetAsync(d_ws, 0, (size_t)N * 16 * 8 + (size_t)N * 4, stream);

    edge_kernel<<<2048, 256, 0, stream>>>(x, ea, eidx, W1, b1, W2, b2, s, cnt, E);
    node_mlp_kernel<<<G, 256, 0, stream>>>(s, cnt, x, root, conv_bias, batch,
                                           ratios, ids, emb,
                                           fc0w, fc0b, fc1w, fc1b, fc2w, fc2b,
                                           (float*)d_out, N);
}